// Round 10
// baseline (245.080 us; speedup 1.0000x reference)
//
#include <hip/hip_runtime.h>
#include <hip/hip_bf16.h>

#define E_EDGES 800000
#define NNODES  50000
#define HID     128

typedef __bf16 bf16x8 __attribute__((ext_vector_type(8)));
typedef float  f32x4  __attribute__((ext_vector_type(4)));
typedef float  f32x2  __attribute__((ext_vector_type(2)));
typedef unsigned short ushortx8 __attribute__((ext_vector_type(8)));

__device__ __forceinline__ unsigned short f2bf(float f) {   // RTNE
    union { float f; unsigned u; } v; v.f = f;
    unsigned r = v.u + 0x7FFFu + ((v.u >> 16) & 1u);
    return (unsigned short)(r >> 16);
}
__device__ __forceinline__ unsigned short f2bf_fast(float f) { // round-half-up
    union { float f; unsigned u; } v; v.f = f;
    return (unsigned short)((v.u + 0x8000u) >> 16);
}
__device__ __forceinline__ float bf2f(unsigned short u) {
    union { unsigned u; float f; } v; v.u = ((unsigned)u) << 16;
    return v.f;
}
// silu without IEEE-divide expansion: mul, exp, add, rcp, mul
__device__ __forceinline__ float silu_fast(float x) {
    float e = __expf(-x);
    return x * __builtin_amdgcn_rcpf(1.0f + e);
}
// decode 8 fp8-e4m3 (two dwords) -> 8 f32 via HW cvt (4 ops)
__device__ __forceinline__ void fp8x8_to_f32(unsigned a, unsigned b, float o[8]) {
    f32x2 x = __builtin_amdgcn_cvt_pk_f32_fp8(a, false);
    f32x2 y = __builtin_amdgcn_cvt_pk_f32_fp8(a, true);
    f32x2 z = __builtin_amdgcn_cvt_pk_f32_fp8(b, false);
    f32x2 w = __builtin_amdgcn_cvt_pk_f32_fp8(b, true);
    o[0] = x[0]; o[1] = x[1]; o[2] = y[0]; o[3] = y[1];
    o[4] = z[0]; o[5] = z[1]; o[6] = w[0]; o[7] = w[1];
}

// ---- prep: weight packing (+ optional out:=coord for the fallback path) ----
__global__ void prep(const float* __restrict__ W1, const float* __restrict__ b1,
                     const float* __restrict__ W2, const float* __restrict__ b2,
                     const float* __restrict__ W3,
                     const float* __restrict__ coord, float* __restrict__ out,
                     unsigned short* __restrict__ W1p, unsigned short* __restrict__ W2p,
                     float4* __restrict__ Wext, float2* __restrict__ W3b2,
                     float2* __restrict__ Eea, int do_copy) {
    int i = blockIdx.x * 256 + threadIdx.x;
    if (do_copy && i < 3 * NNODES) out[i] = coord[i];
    if (i < 32768) {
        int j = i & 7, lane = (i >> 3) & 63, nt = (i >> 9) & 7, kc = i >> 12;
        int n = lane & 15, quad = lane >> 4;
        int k = kc * 32 + quad * 8 + j;
        W1p[i] = f2bf(W1[(nt * 16 + n) * 258 + k]);
    } else if (i < 49152) {
        int t = i - 32768;
        int j = t & 7, lane = (t >> 3) & 63, nt = (t >> 9) & 7, kc = t >> 12;
        int n = lane & 15, quad = lane >> 4;
        int p = kc * 32 + quad * 8 + j;
        int f = (p & 7) * 16 + (p >> 3);
        W2p[t] = f2bf(W2[(nt * 16 + n) * 128 + f]);
    } else if (i < 49280) {
        int c = i - 49152;
        Wext[c] = make_float4(W1[c * 258 + 256], W1[c * 258 + 257], b1[c], b2[c]);
    } else if (i < 49408) {
        int c = i - 49280;
        W3b2[c] = make_float2(W3[c], b2[c]);
    } else if (i < 49536) {
        int p = i - 49408;
        int f = (p & 7) * 16 + (p >> 3);
        Eea[p] = make_float2(W1[f * 258 + 256], W1[f * 258 + 257]);
    }
}

// ---- node projection, P and Q fused, fp8 output, WIDE-GATHER layout ----
// PQb[node] = 256 BYTES: [0,128) = P (h@W1a^T+b1) fp8-e4m3, [128,256) = Q.
// Byte layout chosen so the edge kernel's per-lane 4 kc-fragments are
// CONTIGUOUS 32B: old position p lives at byte b = (p>>3&3)*32+(p>>5)*8+(p&7).
// Producer-side that means lane n's 8 values (positions n*8+nt) go to the
// contiguous chunk (n&3)*32+(n>>2)*8. Also absorbs the out:=coord copy
// (grid 200K threads >= 150K), letting prep shrink to packing only.
__launch_bounds__(256)
__global__ void node_gemm_f(const float* __restrict__ h,
                            const ushortx8* __restrict__ W1p,
                            const float* __restrict__ b1,
                            const float* __restrict__ coord,
                            float* __restrict__ out,
                            unsigned char* __restrict__ PQb) {
    {   // out := coord (was prep's job on the full path)
        int gi = blockIdx.x * 256 + threadIdx.x;
        if (gi < 3 * NNODES) out[gi] = coord[gi];
    }
    const int w    = threadIdx.x >> 6;
    const int lane = threadIdx.x & 63;
    const int n    = lane & 15;
    const int quad = lane >> 4;
    const int base = (blockIdx.x * 4 + w) * 16;

    int nodeA = base + n;
    if (nodeA >= NNODES) nodeA = NNODES - 1;

    const f32x4 zero = { 0.f, 0.f, 0.f, 0.f };
    f32x4 accP[8], accQ[8];
#pragma unroll
    for (int nt = 0; nt < 8; ++nt) { accP[nt] = zero; accQ[nt] = zero; }

#pragma unroll
    for (int kc = 0; kc < 4; ++kc) {
        const float* p = h + (long)nodeA * HID + kc * 32 + quad * 8;
        float4 lo = *(const float4*)p;
        float4 hi = *(const float4*)(p + 4);
        ushortx8 uu;
        uu[0] = f2bf(lo.x); uu[1] = f2bf(lo.y); uu[2] = f2bf(lo.z); uu[3] = f2bf(lo.w);
        uu[4] = f2bf(hi.x); uu[5] = f2bf(hi.y); uu[6] = f2bf(hi.z); uu[7] = f2bf(hi.w);
        bf16x8 af = __builtin_bit_cast(bf16x8, uu);
#pragma unroll
        for (int nt = 0; nt < 8; ++nt) {
            bf16x8 bP = __builtin_bit_cast(bf16x8, W1p[(kc * 8 + nt) * 64 + lane]);
            bf16x8 bQ = __builtin_bit_cast(bf16x8, W1p[((4 + kc) * 8 + nt) * 64 + lane]);
            accP[nt] = __builtin_amdgcn_mfma_f32_16x16x32_bf16(af, bP, accP[nt], 0, 0, 0);
            accQ[nt] = __builtin_amdgcn_mfma_f32_16x16x32_bf16(af, bQ, accQ[nt], 0, 0, 0);
        }
    }

    float b1v[8];
#pragma unroll
    for (int nt = 0; nt < 8; ++nt) b1v[nt] = b1[nt * 16 + n];

    const int boff = (n & 3) * 32 + (n >> 2) * 8;   // wide-gather byte permutation
#pragma unroll
    for (int r = 0; r < 4; ++r) {
        int node = base + quad * 4 + r;
        if (node < NNODES) {
            float pv[8], qv[8];
#pragma unroll
            for (int nt = 0; nt < 8; ++nt) {
                pv[nt] = accP[nt][r] + b1v[nt];
                qv[nt] = accQ[nt][r];
            }
            unsigned int p0 = 0, p1 = 0, q0 = 0, q1 = 0;
            p0 = __builtin_amdgcn_cvt_pk_fp8_f32(pv[0], pv[1], p0, false);
            p0 = __builtin_amdgcn_cvt_pk_fp8_f32(pv[2], pv[3], p0, true);
            p1 = __builtin_amdgcn_cvt_pk_fp8_f32(pv[4], pv[5], p1, false);
            p1 = __builtin_amdgcn_cvt_pk_fp8_f32(pv[6], pv[7], p1, true);
            q0 = __builtin_amdgcn_cvt_pk_fp8_f32(qv[0], qv[1], q0, false);
            q0 = __builtin_amdgcn_cvt_pk_fp8_f32(qv[2], qv[3], q0, true);
            q1 = __builtin_amdgcn_cvt_pk_fp8_f32(qv[4], qv[5], q1, false);
            q1 = __builtin_amdgcn_cvt_pk_fp8_f32(qv[6], qv[7], q1, true);
            uint2 uP; uP.x = p0; uP.y = p1;
            uint2 uQ; uQ.x = q0; uQ.y = q1;
            *(uint2*)(PQb + (long)node * 256 + boff) = uP;
            *(uint2*)(PQb + (long)node * 256 + 128 + boff) = uQ;
        }
    }
}

// ---- edge kernel v11: r9 structure (256 thr, T=4, 2-slot ping-pong, LDS
// weights, wide fp8 gathers, depth-1 prefetch, launch_bounds(256,4)) + 2 cuts:
//  (1) cdiff: 3 dword loads -> 1 dwordx3 (float3), -2 VMEM slots/tile
//  (2) s_setprio(1) around the MFMA cluster (T5): waves here free-run (no
//      in-loop barrier) = the regime where setprio paid +4-7% (m191 attn);
//      boosts MFMA-entering waves over gather-stalled siblings on the CU.
__launch_bounds__(256, 4)
__global__ void edge16p4(const unsigned char* __restrict__ PQb,
                         const int* __restrict__ ei,
                         const float* __restrict__ cdiff,
                         const float2* __restrict__ eattr,
                         const ushortx8* __restrict__ W2p,
                         const float4* __restrict__ Eea4,
                         const float2* __restrict__ W3b2,
                         float* __restrict__ out) {
    constexpr int T = 4;
    __shared__ __align__(16) ushortx8 sW2[2048];   // 32 KB, same layout as W2p
    __shared__ __align__(16) float4   sEea[64];    // 1 KB
    __shared__ __align__(8)  float2   sW3[128];    // 1 KB  {W3, b2}

    const int tid  = threadIdx.x;
    const int lane = tid & 63;
    const int n    = lane & 15;
    const int quad = lane >> 4;
    const int base = ((blockIdx.x * 4) + (tid >> 6)) * (16 * T);

    // ---- stage loop-invariant weights once per block ----
#pragma unroll
    for (int i = 0; i < 8; ++i) sW2[i * 256 + tid] = W2p[i * 256 + tid];
    if (tid < 64) sEea[tid] = Eea4[tid];
    if (tid >= 64 && tid < 192) sW3[tid - 64] = W3b2[tid - 64];
    __syncthreads();

    int ri[T], ci[T];
    float2 ea[T];
    uint4 pfw[2][2], qfw[2][2];   // ping-pong fp8 fragment slots (wide)

    auto loadIdx = [&](int t) {
        int el = base + t * 16 + n;
        ri[t] = ei[el];
        ci[t] = ei[E_EDGES + el];
        ea[t] = eattr[el];
    };
    auto loadPQ = [&](int t, int s) {
        const unsigned char* Pb = PQb + (long)ri[t] * 256 + quad * 32;
        const unsigned char* Qb = PQb + (long)ci[t] * 256 + 128 + quad * 32;
        pfw[s][0] = *(const uint4*)Pb;
        pfw[s][1] = *(const uint4*)(Pb + 16);
        qfw[s][0] = *(const uint4*)Qb;
        qfw[s][1] = *(const uint4*)(Qb + 16);
    };

    // all index loads up-front (latency fully hidden), then depth-1 PQ prefetch
#pragma unroll
    for (int t = 0; t < T; ++t) loadIdx(t);
    loadPQ(0, 0);

#pragma unroll
    for (int t = 0; t < T; ++t) {
        const int s = t & 1;
        if (t + 1 < T) loadPQ(t + 1, s ^ 1);
        // ALU/MFMA may cross, VMEM/DS may not: keep prefetch issued above compute.
        __builtin_amdgcn_sched_barrier(0x9);

        float c0 = 0.f, c1 = 0.f, c2 = 0.f;
        if (lane < 16) {
            long e2 = base + t * 16 + lane;
            float3 cd = *(const float3*)(cdiff + 3 * e2);   // single dwordx3
            c0 = cd.x; c1 = cd.y; c2 = cd.z;
        }

        ushortx8 u[4];
#pragma unroll
        for (int kc = 0; kc < 4; ++kc) {
            uint4 Pw = (kc < 2) ? pfw[s][0] : pfw[s][1];
            uint4 Qw = (kc < 2) ? qfw[s][0] : qfw[s][1];
            unsigned pa = (kc & 1) ? Pw.z : Pw.x;
            unsigned pb = (kc & 1) ? Pw.w : Pw.y;
            unsigned qa = (kc & 1) ? Qw.z : Qw.x;
            unsigned qb = (kc & 1) ? Qw.w : Qw.y;
            float pv[8], qv[8];
            fp8x8_to_f32(pa, pb, pv);
            fp8x8_to_f32(qa, qb, qv);
            float4 ef[4];
#pragma unroll
            for (int q2 = 0; q2 < 4; ++q2) ef[q2] = sEea[kc * 16 + quad * 4 + q2];
#pragma unroll
            for (int j = 0; j < 8; ++j) {
                float ex = (j & 1) ? ef[j >> 1].z : ef[j >> 1].x;
                float ey = (j & 1) ? ef[j >> 1].w : ef[j >> 1].y;
                float v = pv[j] + qv[j] + ea[t].x * ex + ea[t].y * ey;
                u[kc][j] = f2bf_fast(silu_fast(v));
            }
        }

        const f32x4 zero = { 0.f, 0.f, 0.f, 0.f };
        f32x4 acc[8];
#pragma unroll
        for (int nt = 0; nt < 8; ++nt) acc[nt] = zero;
        __builtin_amdgcn_s_setprio(1);
#pragma unroll
        for (int kc = 0; kc < 4; ++kc) {
            bf16x8 af = __builtin_bit_cast(bf16x8, u[kc]);
#pragma unroll
            for (int nt = 0; nt < 8; ++nt) {
                bf16x8 bf = __builtin_bit_cast(bf16x8, sW2[(kc * 8 + nt) * 64 + lane]);
                acc[nt] = __builtin_amdgcn_mfma_f32_16x16x32_bf16(af, bf, acc[nt], 0, 0, 0);
            }
        }
        __builtin_amdgcn_s_setprio(0);

        float part[4] = { 0.f, 0.f, 0.f, 0.f };
#pragma unroll
        for (int nt = 0; nt < 8; ++nt) {
            float2 wb = sW3[nt * 16 + n];   // {W3, b2}
#pragma unroll
            for (int r = 0; r < 4; ++r)
                part[r] += silu_fast(acc[nt][r] + wb.y) * wb.x;
        }
#pragma unroll
        for (int mask = 1; mask < 16; mask <<= 1)
#pragma unroll
            for (int r = 0; r < 4; ++r)
                part[r] += __shfl_xor(part[r], mask, 64);

        float sres = 0.f;
#pragma unroll
        for (int r = 0; r < 4; ++r) {
            float t2 = __shfl(part[r], ((lane & 15) >> 2) * 16, 64);
            if ((lane & 3) == r) sres = t2;
        }

        if (lane < 16) {
            float ex2 = __expf(2.0f * sres);
            float tt = (1.0f - 2.0f * __builtin_amdgcn_rcpf(ex2 + 1.0f)) * 0.15f; // tanh*0.15
            int r = ri[t];   // lane<16: n == lane
            atomicAdd(&out[r * 3 + 0], c0 * tt);
            atomicAdd(&out[r * 3 + 1], c1 * tt);
            atomicAdd(&out[r * 3 + 2], c2 * tt);
        }
    }
}

// ---- fallback (ws too small): round-5 validated ----
__launch_bounds__(256)
__global__ void edge_fb(const float* __restrict__ h, const int* __restrict__ ei,
                        const float* __restrict__ cdiff, const float* __restrict__ eattr,
                        const ushortx8* __restrict__ W1p, const ushortx8* __restrict__ W2p,
                        const float4* __restrict__ Wext, const float* __restrict__ W3,
                        float* __restrict__ out) {
    __shared__ __align__(16) unsigned short x1[4][32][136];
    __shared__ int   rowi[4][32];
    __shared__ int   coli[4][32];
    __shared__ float ea0[4][32];
    __shared__ float ea1[4][32];
    __shared__ float sbuf[4][32];

    const int w = threadIdx.x >> 6, lane = threadIdx.x & 63;
    const int n = lane & 15, quad = lane >> 4;
    const int ebase = (blockIdx.x * 4 + w) * 32;

    if (lane < 32) {
        int e = ebase + lane;
        rowi[w][lane] = ei[e];
        coli[w][lane] = ei[E_EDGES + e];
        const float2 ea = *(const float2*)(eattr + 2 * (long)e);
        ea0[w][lane] = ea.x; ea1[w][lane] = ea.y;
    }
    __syncthreads();

    int nodeR[2] = { rowi[w][n], rowi[w][16 + n] };
    int nodeC[2] = { coli[w][n], coli[w][16 + n] };

    const f32x4 zero = { 0.f, 0.f, 0.f, 0.f };
    f32x4 acc[2][8];
#pragma unroll
    for (int mt = 0; mt < 2; ++mt)
#pragma unroll
        for (int nt = 0; nt < 8; ++nt) acc[mt][nt] = zero;

#pragma unroll
    for (int kc = 0; kc < 8; ++kc) {
        bf16x8 afrag[2];
#pragma unroll
        for (int mt = 0; mt < 2; ++mt) {
            int node = (kc < 4) ? nodeR[mt] : nodeC[mt];
            const float* p = h + (long)node * HID + (kc & 3) * 32 + quad * 8;
            float4 lo = *(const float4*)p;
            float4 hi = *(const float4*)(p + 4);
            ushortx8 u;
            u[0] = f2bf(lo.x); u[1] = f2bf(lo.y); u[2] = f2bf(lo.z); u[3] = f2bf(lo.w);
            u[4] = f2bf(hi.x); u[5] = f2bf(hi.y); u[6] = f2bf(hi.z); u[7] = f2bf(hi.w);
            afrag[mt] = __builtin_bit_cast(bf16x8, u);
        }
#pragma unroll
        for (int nt = 0; nt < 8; ++nt) {
            bf16x8 bfrag = __builtin_bit_cast(bf16x8, W1p[(kc * 8 + nt) * 64 + lane]);
            acc[0][nt] = __builtin_amdgcn_mfma_f32_16x16x32_bf16(afrag[0], bfrag, acc[0][nt], 0, 0, 0);
            acc[1][nt] = __builtin_amdgcn_mfma_f32_16x16x32_bf16(afrag[1], bfrag, acc[1][nt], 0, 0, 0);
        }
    }

    float b2v[8];
    {
        float4 wx[8];
#pragma unroll
        for (int nt = 0; nt < 8; ++nt) wx[nt] = Wext[nt * 16 + n];
#pragma unroll
        for (int nt = 0; nt < 8; ++nt) b2v[nt] = wx[nt].w;
#pragma unroll
        for (int mt = 0; mt < 2; ++mt) {
#pragma unroll
            for (int r = 0; r < 4; ++r) {
                int m = mt * 16 + quad * 4 + r;
                float a0 = ea0[w][m], a1 = ea1[w][m];
                ushortx8 u;
#pragma unroll
                for (int nt = 0; nt < 8; ++nt) {
                    float v = acc[mt][nt][r] + wx[nt].z + a0 * wx[nt].x + a1 * wx[nt].y;
                    u[nt] = f2bf(silu_fast(v));
                }
                *(ushortx8*)&x1[w][m][n * 8] = u;
            }
        }
    }
    __syncthreads();

#pragma unroll
    for (int mt = 0; mt < 2; ++mt)
#pragma unroll
        for (int nt = 0; nt < 8; ++nt) acc[mt][nt] = zero;

#pragma unroll
    for (int kc = 0; kc < 4; ++kc) {
        bf16x8 afrag[2];
#pragma unroll
        for (int mt = 0; mt < 2; ++mt)
            afrag[mt] = __builtin_bit_cast(bf16x8, *(const ushortx8*)&x1[w][mt * 16 + n][kc * 32 + quad * 8]);
#pragma unroll
        for (int nt = 0; nt < 8; ++nt) {
            bf16x8 bfrag = __builtin_bit_cast(bf16x8, W2p[(kc * 8 + nt) * 64 + lane]);
            acc[0][nt] = __builtin_amdgcn_mfma_f32_16x16x32_bf16(afrag[0], bfrag, acc[0][nt], 0, 0, 0);
            acc[1][nt] = __builtin_amdgcn_mfma_f32_16x16x32_bf16(afrag[1], bfrag, acc[1][nt], 0, 0, 0);
        }
    }

    float part[2][4] = { {0.f,0.f,0.f,0.f}, {0.f,0.f,0.f,0.f} };
#pragma unroll
    for (int nt = 0; nt < 8; ++nt) {
        float w3 = W3[nt * 16 + n];
#pragma unroll
        for (int mt = 0; mt < 2; ++mt)
#pragma unroll
            for (int r = 0; r < 4; ++r)
                part[mt][r] += silu_fast(acc[mt][nt][r] + b2v[nt]) * w3;
    }
#pragma unroll
    for (int mask = 1; mask < 16; mask <<= 1)
#pragma unroll
        for (int mt = 0; mt < 2; ++mt)
#pragma unroll
            for (int r = 0; r < 4; ++r)
                part[mt][r] += __shfl_xor(part[mt][r], mask, 64);

    if (n == 0) {
#pragma unroll
        for (int mt = 0; mt < 2; ++mt)
#pragma unroll
            for (int r = 0; r < 4; ++r)
                sbuf[w][mt * 16 + quad * 4 + r] = part[mt][r];
    }
    __syncthreads();

    if (lane < 32) {
        int e = ebase + lane;
        float s = sbuf[w][lane];
        float ex = __expf(2.0f * s);
        float t = (1.0f - 2.0f * __builtin_amdgcn_rcpf(ex + 1.0f)) * 0.15f;
        float c0 = cdiff[3 * (long)e + 0];
        float c1 = cdiff[3 * (long)e + 1];
        float c2 = cdiff[3 * (long)e + 2];
        int r = rowi[w][lane];
        atomicAdd(&out[r * 3 + 0], c0 * t);
        atomicAdd(&out[r * 3 + 1], c1 * t);
        atomicAdd(&out[r * 3 + 2], c2 * t);
    }
}

extern "C" void kernel_launch(void* const* d_in, const int* in_sizes, int n_in,
                              void* d_out, int out_size, void* d_ws, size_t ws_size,
                              hipStream_t stream) {
    const float* h     = (const float*)d_in[0];
    const float* coord = (const float*)d_in[1];
    const int*   ei    = (const int*)d_in[2];
    const float* cdiff = (const float*)d_in[3];
    const float* eattr = (const float*)d_in[4];
    const float* W1    = (const float*)d_in[5];
    const float* b1    = (const float*)d_in[6];
    const float* W2    = (const float*)d_in[7];
    const float* b2    = (const float*)d_in[8];
    const float* W3    = (const float*)d_in[9];
    float* out = (float*)d_out;

    char* ws = (char*)d_ws;
    unsigned short* W1p  = (unsigned short*)ws;                  // 65536 B
    unsigned short* W2p  = (unsigned short*)(ws + 65536);        // 32768 B
    float4*         Wext = (float4*)(ws + 98304);                // 2048 B
    float2*         W3b2 = (float2*)(ws + 100352);               // 1024 B
    float2*         Eea  = (float2*)(ws + 101376);               // 1024 B
    unsigned char*  PQb  = (unsigned char*)(ws + 102400);        // 12.8 MB (fp8)
    const size_t need_full = 102400ull + 12800000ull;

    if (ws_size >= need_full) {
        // full path: prep = packing only (194 blocks); node_gemm does the copy
        prep<<<194, 256, 0, stream>>>(W1, b1, W2, b2, W3, coord, out,
                                      W1p, W2p, Wext, W3b2, Eea, 0);
        node_gemm_f<<<(NNODES + 63) / 64, 256, 0, stream>>>(h, (const ushortx8*)W1p, b1,
                                                            coord, out, PQb);
        edge16p4<<<E_EDGES / 256, 256, 0, stream>>>(PQb, ei, cdiff, (const float2*)eattr,
                                                    (const ushortx8*)W2p, (const float4*)Eea,
                                                    (const float2*)W3b2, out);
    } else {
        prep<<<(3 * NNODES + 255) / 256, 256, 0, stream>>>(W1, b1, W2, b2, W3, coord, out,
                                                           W1p, W2p, Wext, W3b2, Eea, 1);
        edge_fb<<<E_EDGES / 128, 256, 0, stream>>>(h, ei, cdiff, eattr,
                                                   (const ushortx8*)W1p, (const ushortx8*)W2p,
                                                   (const float4*)Wext, W3, out);
    }
}

// Round 11
// 184.283 us; speedup vs baseline: 1.3299x; 1.3299x over previous
//
#include <hip/hip_runtime.h>
#include <hip/hip_bf16.h>

#define E_EDGES 800000
#define NNODES  50000
#define HID     128

typedef __bf16 bf16x8 __attribute__((ext_vector_type(8)));
typedef float  f32x4  __attribute__((ext_vector_type(4)));
typedef float  f32x2  __attribute__((ext_vector_type(2)));
typedef unsigned short ushortx8 __attribute__((ext_vector_type(8)));

__device__ __forceinline__ unsigned short f2bf(float f) {   // RTNE
    union { float f; unsigned u; } v; v.f = f;
    unsigned r = v.u + 0x7FFFu + ((v.u >> 16) & 1u);
    return (unsigned short)(r >> 16);
}
__device__ __forceinline__ unsigned short f2bf_fast(float f) { // round-half-up
    union { float f; unsigned u; } v; v.f = f;
    return (unsigned short)((v.u + 0x8000u) >> 16);
}
__device__ __forceinline__ float bf2f(unsigned short u) {
    union { unsigned u; float f; } v; v.u = ((unsigned)u) << 16;
    return v.f;
}
// silu without IEEE-divide expansion: mul, exp, add, rcp, mul
__device__ __forceinline__ float silu_fast(float x) {
    float e = __expf(-x);
    return x * __builtin_amdgcn_rcpf(1.0f + e);
}
// decode 8 fp8-e4m3 (two dwords) -> 8 f32 via HW cvt (4 ops)
__device__ __forceinline__ void fp8x8_to_f32(unsigned a, unsigned b, float o[8]) {
    f32x2 x = __builtin_amdgcn_cvt_pk_f32_fp8(a, false);
    f32x2 y = __builtin_amdgcn_cvt_pk_f32_fp8(a, true);
    f32x2 z = __builtin_amdgcn_cvt_pk_f32_fp8(b, false);
    f32x2 w = __builtin_amdgcn_cvt_pk_f32_fp8(b, true);
    o[0] = x[0]; o[1] = x[1]; o[2] = y[0]; o[3] = y[1];
    o[4] = z[0]; o[5] = z[1]; o[6] = w[0]; o[7] = w[1];
}

// ---- prep: weight packing (+ optional out:=coord for the fallback path) ----
__global__ void prep(const float* __restrict__ W1, const float* __restrict__ b1,
                     const float* __restrict__ W2, const float* __restrict__ b2,
                     const float* __restrict__ W3,
                     const float* __restrict__ coord, float* __restrict__ out,
                     unsigned short* __restrict__ W1p, unsigned short* __restrict__ W2p,
                     float4* __restrict__ Wext, float2* __restrict__ W3b2,
                     float2* __restrict__ Eea, int do_copy) {
    int i = blockIdx.x * 256 + threadIdx.x;
    if (do_copy && i < 3 * NNODES) out[i] = coord[i];
    if (i < 32768) {
        int j = i & 7, lane = (i >> 3) & 63, nt = (i >> 9) & 7, kc = i >> 12;
        int n = lane & 15, quad = lane >> 4;
        int k = kc * 32 + quad * 8 + j;
        W1p[i] = f2bf(W1[(nt * 16 + n) * 258 + k]);
    } else if (i < 49152) {
        int t = i - 32768;
        int j = t & 7, lane = (t >> 3) & 63, nt = (t >> 9) & 7, kc = t >> 12;
        int n = lane & 15, quad = lane >> 4;
        int p = kc * 32 + quad * 8 + j;
        int f = (p & 7) * 16 + (p >> 3);
        W2p[t] = f2bf(W2[(nt * 16 + n) * 128 + f]);
    } else if (i < 49280) {
        int c = i - 49152;
        Wext[c] = make_float4(W1[c * 258 + 256], W1[c * 258 + 257], b1[c], b2[c]);
    } else if (i < 49408) {
        int c = i - 49280;
        W3b2[c] = make_float2(W3[c], b2[c]);
    } else if (i < 49536) {
        int p = i - 49408;
        int f = (p & 7) * 16 + (p >> 3);
        Eea[p] = make_float2(W1[f * 258 + 256], W1[f * 258 + 257]);
    }
}

// ---- node projection, P and Q fused, fp8 output, WIDE-GATHER layout ----
// PQb[node] = 256 BYTES: [0,128) = P (h@W1a^T+b1) fp8-e4m3, [128,256) = Q.
// Byte layout chosen so the edge kernel's per-lane 4 kc-fragments are
// CONTIGUOUS 32B: old position p lives at byte b = (p>>3&3)*32+(p>>5)*8+(p&7).
// Producer-side that means lane n's 8 values (positions n*8+nt) go to the
// contiguous chunk (n&3)*32+(n>>2)*8. Also absorbs the out:=coord copy
// (grid 200K threads >= 150K), letting prep shrink to packing only.
__launch_bounds__(256)
__global__ void node_gemm_f(const float* __restrict__ h,
                            const ushortx8* __restrict__ W1p,
                            const float* __restrict__ b1,
                            const float* __restrict__ coord,
                            float* __restrict__ out,
                            unsigned char* __restrict__ PQb) {
    {   // out := coord (was prep's job on the full path)
        int gi = blockIdx.x * 256 + threadIdx.x;
        if (gi < 3 * NNODES) out[gi] = coord[gi];
    }
    const int w    = threadIdx.x >> 6;
    const int lane = threadIdx.x & 63;
    const int n    = lane & 15;
    const int quad = lane >> 4;
    const int base = (blockIdx.x * 4 + w) * 16;

    int nodeA = base + n;
    if (nodeA >= NNODES) nodeA = NNODES - 1;

    const f32x4 zero = { 0.f, 0.f, 0.f, 0.f };
    f32x4 accP[8], accQ[8];
#pragma unroll
    for (int nt = 0; nt < 8; ++nt) { accP[nt] = zero; accQ[nt] = zero; }

#pragma unroll
    for (int kc = 0; kc < 4; ++kc) {
        const float* p = h + (long)nodeA * HID + kc * 32 + quad * 8;
        float4 lo = *(const float4*)p;
        float4 hi = *(const float4*)(p + 4);
        ushortx8 uu;
        uu[0] = f2bf(lo.x); uu[1] = f2bf(lo.y); uu[2] = f2bf(lo.z); uu[3] = f2bf(lo.w);
        uu[4] = f2bf(hi.x); uu[5] = f2bf(hi.y); uu[6] = f2bf(hi.z); uu[7] = f2bf(hi.w);
        bf16x8 af = __builtin_bit_cast(bf16x8, uu);
#pragma unroll
        for (int nt = 0; nt < 8; ++nt) {
            bf16x8 bP = __builtin_bit_cast(bf16x8, W1p[(kc * 8 + nt) * 64 + lane]);
            bf16x8 bQ = __builtin_bit_cast(bf16x8, W1p[((4 + kc) * 8 + nt) * 64 + lane]);
            accP[nt] = __builtin_amdgcn_mfma_f32_16x16x32_bf16(af, bP, accP[nt], 0, 0, 0);
            accQ[nt] = __builtin_amdgcn_mfma_f32_16x16x32_bf16(af, bQ, accQ[nt], 0, 0, 0);
        }
    }

    float b1v[8];
#pragma unroll
    for (int nt = 0; nt < 8; ++nt) b1v[nt] = b1[nt * 16 + n];

    const int boff = (n & 3) * 32 + (n >> 2) * 8;   // wide-gather byte permutation
#pragma unroll
    for (int r = 0; r < 4; ++r) {
        int node = base + quad * 4 + r;
        if (node < NNODES) {
            float pv[8], qv[8];
#pragma unroll
            for (int nt = 0; nt < 8; ++nt) {
                pv[nt] = accP[nt][r] + b1v[nt];
                qv[nt] = accQ[nt][r];
            }
            unsigned int p0 = 0, p1 = 0, q0 = 0, q1 = 0;
            p0 = __builtin_amdgcn_cvt_pk_fp8_f32(pv[0], pv[1], p0, false);
            p0 = __builtin_amdgcn_cvt_pk_fp8_f32(pv[2], pv[3], p0, true);
            p1 = __builtin_amdgcn_cvt_pk_fp8_f32(pv[4], pv[5], p1, false);
            p1 = __builtin_amdgcn_cvt_pk_fp8_f32(pv[6], pv[7], p1, true);
            q0 = __builtin_amdgcn_cvt_pk_fp8_f32(qv[0], qv[1], q0, false);
            q0 = __builtin_amdgcn_cvt_pk_fp8_f32(qv[2], qv[3], q0, true);
            q1 = __builtin_amdgcn_cvt_pk_fp8_f32(qv[4], qv[5], q1, false);
            q1 = __builtin_amdgcn_cvt_pk_fp8_f32(qv[6], qv[7], q1, true);
            uint2 uP; uP.x = p0; uP.y = p1;
            uint2 uQ; uQ.x = q0; uQ.y = q1;
            *(uint2*)(PQb + (long)node * 256 + boff) = uP;
            *(uint2*)(PQb + (long)node * 256 + 128 + boff) = uQ;
        }
    }
}

// ---- edge kernel v12: r9 structure (256 thr, T=4, 2-slot ping-pong, LDS
// weights, wide fp8 gathers, depth-1 prefetch, launch_bounds(256,4)).
// Changes vs r10: setprio REVERTED (neutral-negative, matches m190 GEMM-null);
// atomic tail spread across 48 lanes. Key fact: the existing __shfl broadcast
// already gives EVERY lane sres for edge n=lane&15, and ri[t] is per-lane
// correct — so lanes 0-47 each issue ONE atomic for (edge n, component quad):
// 3 serialized VMEM atomic instructions -> 1, 3x wider issue, -2 VGPR.
__launch_bounds__(256, 4)
__global__ void edge16p4(const unsigned char* __restrict__ PQb,
                         const int* __restrict__ ei,
                         const float* __restrict__ cdiff,
                         const float2* __restrict__ eattr,
                         const ushortx8* __restrict__ W2p,
                         const float4* __restrict__ Eea4,
                         const float2* __restrict__ W3b2,
                         float* __restrict__ out) {
    constexpr int T = 4;
    __shared__ __align__(16) ushortx8 sW2[2048];   // 32 KB, same layout as W2p
    __shared__ __align__(16) float4   sEea[64];    // 1 KB
    __shared__ __align__(8)  float2   sW3[128];    // 1 KB  {W3, b2}

    const int tid  = threadIdx.x;
    const int lane = tid & 63;
    const int n    = lane & 15;
    const int quad = lane >> 4;
    const int base = ((blockIdx.x * 4) + (tid >> 6)) * (16 * T);

    // ---- stage loop-invariant weights once per block ----
#pragma unroll
    for (int i = 0; i < 8; ++i) sW2[i * 256 + tid] = W2p[i * 256 + tid];
    if (tid < 64) sEea[tid] = Eea4[tid];
    if (tid >= 64 && tid < 192) sW3[tid - 64] = W3b2[tid - 64];
    __syncthreads();

    int ri[T], ci[T];
    float2 ea[T];
    uint4 pfw[2][2], qfw[2][2];   // ping-pong fp8 fragment slots (wide)

    auto loadIdx = [&](int t) {
        int el = base + t * 16 + n;
        ri[t] = ei[el];
        ci[t] = ei[E_EDGES + el];
        ea[t] = eattr[el];
    };
    auto loadPQ = [&](int t, int s) {
        const unsigned char* Pb = PQb + (long)ri[t] * 256 + quad * 32;
        const unsigned char* Qb = PQb + (long)ci[t] * 256 + 128 + quad * 32;
        pfw[s][0] = *(const uint4*)Pb;
        pfw[s][1] = *(const uint4*)(Pb + 16);
        qfw[s][0] = *(const uint4*)Qb;
        qfw[s][1] = *(const uint4*)(Qb + 16);
    };

    // all index loads up-front (latency fully hidden), then depth-1 PQ prefetch
#pragma unroll
    for (int t = 0; t < T; ++t) loadIdx(t);
    loadPQ(0, 0);

#pragma unroll
    for (int t = 0; t < T; ++t) {
        const int s = t & 1;
        if (t + 1 < T) loadPQ(t + 1, s ^ 1);
        // ALU/MFMA may cross, VMEM/DS may not: keep prefetch issued above compute.
        __builtin_amdgcn_sched_barrier(0x9);

        float cdv = 0.f;
        if (lane < 48) {   // lane<48: edge n, component quad (one dword, coalesced)
            long e2 = base + t * 16 + n;
            cdv = cdiff[3 * e2 + quad];
        }

        ushortx8 u[4];
#pragma unroll
        for (int kc = 0; kc < 4; ++kc) {
            uint4 Pw = (kc < 2) ? pfw[s][0] : pfw[s][1];
            uint4 Qw = (kc < 2) ? qfw[s][0] : qfw[s][1];
            unsigned pa = (kc & 1) ? Pw.z : Pw.x;
            unsigned pb = (kc & 1) ? Pw.w : Pw.y;
            unsigned qa = (kc & 1) ? Qw.z : Qw.x;
            unsigned qb = (kc & 1) ? Qw.w : Qw.y;
            float pv[8], qv[8];
            fp8x8_to_f32(pa, pb, pv);
            fp8x8_to_f32(qa, qb, qv);
            float4 ef[4];
#pragma unroll
            for (int q2 = 0; q2 < 4; ++q2) ef[q2] = sEea[kc * 16 + quad * 4 + q2];
#pragma unroll
            for (int j = 0; j < 8; ++j) {
                float ex = (j & 1) ? ef[j >> 1].z : ef[j >> 1].x;
                float ey = (j & 1) ? ef[j >> 1].w : ef[j >> 1].y;
                float v = pv[j] + qv[j] + ea[t].x * ex + ea[t].y * ey;
                u[kc][j] = f2bf_fast(silu_fast(v));
            }
        }

        const f32x4 zero = { 0.f, 0.f, 0.f, 0.f };
        f32x4 acc[8];
#pragma unroll
        for (int nt = 0; nt < 8; ++nt) acc[nt] = zero;
#pragma unroll
        for (int kc = 0; kc < 4; ++kc) {
            bf16x8 af = __builtin_bit_cast(bf16x8, u[kc]);
#pragma unroll
            for (int nt = 0; nt < 8; ++nt) {
                bf16x8 bf = __builtin_bit_cast(bf16x8, sW2[(kc * 8 + nt) * 64 + lane]);
                acc[nt] = __builtin_amdgcn_mfma_f32_16x16x32_bf16(af, bf, acc[nt], 0, 0, 0);
            }
        }

        float part[4] = { 0.f, 0.f, 0.f, 0.f };
#pragma unroll
        for (int nt = 0; nt < 8; ++nt) {
            float2 wb = sW3[nt * 16 + n];   // {W3, b2}
#pragma unroll
            for (int r = 0; r < 4; ++r)
                part[r] += silu_fast(acc[nt][r] + wb.y) * wb.x;
        }
#pragma unroll
        for (int mask = 1; mask < 16; mask <<= 1)
#pragma unroll
            for (int r = 0; r < 4; ++r)
                part[r] += __shfl_xor(part[r], mask, 64);

        float sres = 0.f;
#pragma unroll
        for (int r = 0; r < 4; ++r) {
            float t2 = __shfl(part[r], ((lane & 15) >> 2) * 16, 64);
            if ((lane & 3) == r) sres = t2;
        }
        // after the shfl broadcast, EVERY lane holds sres for edge n = lane&15

        if (lane < 48) {
            float ex2 = __expf(2.0f * sres);
            float tt = (1.0f - 2.0f * __builtin_amdgcn_rcpf(ex2 + 1.0f)) * 0.15f; // tanh*0.15
            atomicAdd(&out[ri[t] * 3 + quad], cdv * tt);   // one atomic per lane
        }
    }
}

// ---- fallback (ws too small): round-5 validated ----
__launch_bounds__(256)
__global__ void edge_fb(const float* __restrict__ h, const int* __restrict__ ei,
                        const float* __restrict__ cdiff, const float* __restrict__ eattr,
                        const ushortx8* __restrict__ W1p, const ushortx8* __restrict__ W2p,
                        const float4* __restrict__ Wext, const float* __restrict__ W3,
                        float* __restrict__ out) {
    __shared__ __align__(16) unsigned short x1[4][32][136];
    __shared__ int   rowi[4][32];
    __shared__ int   coli[4][32];
    __shared__ float ea0[4][32];
    __shared__ float ea1[4][32];
    __shared__ float sbuf[4][32];

    const int w = threadIdx.x >> 6, lane = threadIdx.x & 63;
    const int n = lane & 15, quad = lane >> 4;
    const int ebase = (blockIdx.x * 4 + w) * 32;

    if (lane < 32) {
        int e = ebase + lane;
        rowi[w][lane] = ei[e];
        coli[w][lane] = ei[E_EDGES + e];
        const float2 ea = *(const float2*)(eattr + 2 * (long)e);
        ea0[w][lane] = ea.x; ea1[w][lane] = ea.y;
    }
    __syncthreads();

    int nodeR[2] = { rowi[w][n], rowi[w][16 + n] };
    int nodeC[2] = { coli[w][n], coli[w][16 + n] };

    const f32x4 zero = { 0.f, 0.f, 0.f, 0.f };
    f32x4 acc[2][8];
#pragma unroll
    for (int mt = 0; mt < 2; ++mt)
#pragma unroll
        for (int nt = 0; nt < 8; ++nt) acc[mt][nt] = zero;

#pragma unroll
    for (int kc = 0; kc < 8; ++kc) {
        bf16x8 afrag[2];
#pragma unroll
        for (int mt = 0; mt < 2; ++mt) {
            int node = (kc < 4) ? nodeR[mt] : nodeC[mt];
            const float* p = h + (long)node * HID + (kc & 3) * 32 + quad * 8;
            float4 lo = *(const float4*)p;
            float4 hi = *(const float4*)(p + 4);
            ushortx8 u;
            u[0] = f2bf(lo.x); u[1] = f2bf(lo.y); u[2] = f2bf(lo.z); u[3] = f2bf(lo.w);
            u[4] = f2bf(hi.x); u[5] = f2bf(hi.y); u[6] = f2bf(hi.z); u[7] = f2bf(hi.w);
            afrag[mt] = __builtin_bit_cast(bf16x8, u);
        }
#pragma unroll
        for (int nt = 0; nt < 8; ++nt) {
            bf16x8 bfrag = __builtin_bit_cast(bf16x8, W1p[(kc * 8 + nt) * 64 + lane]);
            acc[0][nt] = __builtin_amdgcn_mfma_f32_16x16x32_bf16(afrag[0], bfrag, acc[0][nt], 0, 0, 0);
            acc[1][nt] = __builtin_amdgcn_mfma_f32_16x16x32_bf16(afrag[1], bfrag, acc[1][nt], 0, 0, 0);
        }
    }

    float b2v[8];
    {
        float4 wx[8];
#pragma unroll
        for (int nt = 0; nt < 8; ++nt) wx[nt] = Wext[nt * 16 + n];
#pragma unroll
        for (int nt = 0; nt < 8; ++nt) b2v[nt] = wx[nt].w;
#pragma unroll
        for (int mt = 0; mt < 2; ++mt) {
#pragma unroll
            for (int r = 0; r < 4; ++r) {
                int m = mt * 16 + quad * 4 + r;
                float a0 = ea0[w][m], a1 = ea1[w][m];
                ushortx8 u;
#pragma unroll
                for (int nt = 0; nt < 8; ++nt) {
                    float v = acc[mt][nt][r] + wx[nt].z + a0 * wx[nt].x + a1 * wx[nt].y;
                    u[nt] = f2bf(silu_fast(v));
                }
                *(ushortx8*)&x1[w][m][n * 8] = u;
            }
        }
    }
    __syncthreads();

#pragma unroll
    for (int mt = 0; mt < 2; ++mt)
#pragma unroll
        for (int nt = 0; nt < 8; ++nt) acc[mt][nt] = zero;

#pragma unroll
    for (int kc = 0; kc < 4; ++kc) {
        bf16x8 afrag[2];
#pragma unroll
        for (int mt = 0; mt < 2; ++mt)
            afrag[mt] = __builtin_bit_cast(bf16x8, *(const ushortx8*)&x1[w][mt * 16 + n][kc * 32 + quad * 8]);
#pragma unroll
        for (int nt = 0; nt < 8; ++nt) {
            bf16x8 bfrag = __builtin_bit_cast(bf16x8, W2p[(kc * 8 + nt) * 64 + lane]);
            acc[0][nt] = __builtin_amdgcn_mfma_f32_16x16x32_bf16(afrag[0], bfrag, acc[0][nt], 0, 0, 0);
            acc[1][nt] = __builtin_amdgcn_mfma_f32_16x16x32_bf16(afrag[1], bfrag, acc[1][nt], 0, 0, 0);
        }
    }

    float part[2][4] = { {0.f,0.f,0.f,0.f}, {0.f,0.f,0.f,0.f} };
#pragma unroll
    for (int nt = 0; nt < 8; ++nt) {
        float w3 = W3[nt * 16 + n];
#pragma unroll
        for (int mt = 0; mt < 2; ++mt)
#pragma unroll
            for (int r = 0; r < 4; ++r)
                part[mt][r] += silu_fast(acc[mt][nt][r] + b2v[nt]) * w3;
    }
#pragma unroll
    for (int mask = 1; mask < 16; mask <<= 1)
#pragma unroll
        for (int mt = 0; mt < 2; ++mt)
#pragma unroll
            for (int r = 0; r < 4; ++r)
                part[mt][r] += __shfl_xor(part[mt][r], mask, 64);

    if (n == 0) {
#pragma unroll
        for (int mt = 0; mt < 2; ++mt)
#pragma unroll
            for (int r = 0; r < 4; ++r)
                sbuf[w][mt * 16 + quad * 4 + r] = part[mt][r];
    }
    __syncthreads();

    if (lane < 32) {
        int e = ebase + lane;
        float s = sbuf[w][lane];
        float ex = __expf(2.0f * s);
        float t = (1.0f - 2.0f * __builtin_amdgcn_rcpf(ex + 1.0f)) * 0.15f;
        float c0 = cdiff[3 * (long)e + 0];
        float c1 = cdiff[3 * (long)e + 1];
        float c2 = cdiff[3 * (long)e + 2];
        int r = rowi[w][lane];
        atomicAdd(&out[r * 3 + 0], c0 * t);
        atomicAdd(&out[r * 3 + 1], c1 * t);
        atomicAdd(&out[r * 3 + 2], c2 * t);
    }
}

extern "C" void kernel_launch(void* const* d_in, const int* in_sizes, int n_in,
                              void* d_out, int out_size, void* d_ws, size_t ws_size,
                              hipStream_t stream) {
    const float* h     = (const float*)d_in[0];
    const float* coord = (const float*)d_in[1];
    const int*   ei    = (const int*)d_in[2];
    const float* cdiff = (const float*)d_in[3];
    const float* eattr = (const float*)d_in[4];
    const float* W1    = (const float*)d_in[5];
    const float* b1    = (const float*)d_in[6];
    const float* W2    = (const float*)d_in[7];
    const float* b2    = (const float*)d_in[8];
    const float* W3    = (const float*)d_in[9];
    float* out = (float*)d_out;

    char* ws = (char*)d_ws;
    unsigned short* W1p  = (unsigned short*)ws;                  // 65536 B
    unsigned short* W2p  = (unsigned short*)(ws + 65536);        // 32768 B
    float4*         Wext = (float4*)(ws + 98304);                // 2048 B
    float2*         W3b2 = (float2*)(ws + 100352);               // 1024 B
    float2*         Eea  = (float2*)(ws + 101376);               // 1024 B
    unsigned char*  PQb  = (unsigned char*)(ws + 102400);        // 12.8 MB (fp8)
    const size_t need_full = 102400ull + 12800000ull;

    if (ws_size >= need_full) {
        // full path: prep = packing only (194 blocks); node_gemm does the copy
        prep<<<194, 256, 0, stream>>>(W1, b1, W2, b2, W3, coord, out,
                                      W1p, W2p, Wext, W3b2, Eea, 0);
        node_gemm_f<<<(NNODES + 63) / 64, 256, 0, stream>>>(h, (const ushortx8*)W1p, b1,
                                                            coord, out, PQb);
        edge16p4<<<E_EDGES / 256, 256, 0, stream>>>(PQb, ei, cdiff, (const float2*)eattr,
                                                    (const ushortx8*)W2p, (const float4*)Eea,
                                                    (const float2*)W3b2, out);
    } else {
        prep<<<(3 * NNODES + 255) / 256, 256, 0, stream>>>(W1, b1, W2, b2, W3, coord, out,
                                                           W1p, W2p, Wext, W3b2, Eea, 1);
        edge_fb<<<E_EDGES / 128, 256, 0, stream>>>(h, ei, cdiff, eattr,
                                                   (const ushortx8*)W1p, (const ushortx8*)W2p,
                                                   (const float4*)Wext, W3, out);
    }
}